// Round 17
// baseline (319.958 us; speedup 1.0000x reference)
//
#include <hip/hip_runtime.h>
#include <math.h>

#define Hd 264
#define Wd 480
#define HW (Hd * Wd)
#define NB 16
#define NC 9
#define KK 50
#define NPLANE 144
#define NDET 800
#define NK 450
#define SCAP 1024
#define FB_CAP 16384
#define TB_F 0.998f
#define PI_F 3.14159274101257324f
#define TWO_PI_F 6.28318548202514648f

__device__ const float DIMM[9][3] = {
    {3.99331126f, 1.54370861f, 1.64175497f},
    {0.295f, 1.6f, 0.3175f},
    {1.34645161f, 1.55322581f, 0.3883871f},
    {2.503f, 1.72f, 1.077f},
    {9.1775f, 2.95f, 2.3425f},
    {10.3655102f, 3.31632653f, 2.45469388f},
    {6.016911083f, 3.412001685f, 2.2783185f},
    {4.824963f, 2.046904f, 1.78939f},
    {8.8040879f, 2.916193f, 2.07649252f}};

__device__ const float ACENT[4] = {0.0f, 1.57079637050628662f, 3.14159274101257324f, -1.57079637050628662f};

__device__ __forceinline__ unsigned long long mkkey(float v, unsigned int idx) {
    return ((unsigned long long)__float_as_uint(v) << 32) | (unsigned long long)(0xFFFFFFFFu - idx);
}

// Kernel 1: one block per plane (144 blocks x 512 threads). Stream the plane
// (float4), threshold >= TB into LDS, NMS-verify candidates with direct
// 25-point window reads (plane L2/L3-hot), exact rank -> planeKeys. All
// block-local; no cross-block reads of fresh data. LDS-append order is
// nondeterministic but rank-by-count-greater is order-independent ->
// planeKeys bit-deterministic (replay-safe). Keys = (value<<32)|~idx.
// Fallback (overflow / <50 survivors): block-local brute-force NMS + argmax.
__global__ __launch_bounds__(512) void plane_select(const float* __restrict__ cls,
                                                    unsigned long long* __restrict__ planeKeys,
                                                    unsigned long long* __restrict__ fbBuf,
                                                    int* __restrict__ fbCnt) {
    __shared__ unsigned long long cand[SCAP];  // 8 KB
    __shared__ unsigned long long S[SCAP];     // 8 KB
    __shared__ int s_cnt, s_scnt;
    __shared__ unsigned long long wmax[8];
    __shared__ unsigned long long sprev;

    const int p = blockIdx.x;
    const int tid = threadIdx.x;
    const int lane = tid & 63, wid = tid >> 6;
    const float* hp = cls + (size_t)p * HW;
    const float4* hp4 = (const float4*)hp;

    if (tid == 0) { s_cnt = 0; s_scnt = 0; }
    __syncthreads();

    // Stream + threshold (62 independent float4 loads per thread).
    for (int q = tid; q < HW / 4; q += 512) {
        const float4 v = hp4[q];
        const unsigned int i0 = 4u * (unsigned int)q;
        if (v.x >= TB_F) { const int c = atomicAdd(&s_cnt, 1); if (c < SCAP) cand[c] = mkkey(v.x, i0); }
        if (v.y >= TB_F) { const int c = atomicAdd(&s_cnt, 1); if (c < SCAP) cand[c] = mkkey(v.y, i0 + 1); }
        if (v.z >= TB_F) { const int c = atomicAdd(&s_cnt, 1); if (c < SCAP) cand[c] = mkkey(v.z, i0 + 2); }
        if (v.w >= TB_F) { const int c = atomicAdd(&s_cnt, 1); if (c < SCAP) cand[c] = mkkey(v.w, i0 + 3); }
    }
    __syncthreads();
    const int cnt = s_cnt;
    const bool over = cnt > SCAP;

    if (!over) {
        // NMS-verify each candidate (25-point window, L2/L3-hot).
        for (int j = tid; j < cnt; j += 512) {
            const unsigned long long k = cand[j];
            const unsigned int idx = 0xFFFFFFFFu - (unsigned int)(k & 0xFFFFFFFFull);
            const float v = __uint_as_float((unsigned int)(k >> 32));
            const int y = (int)idx / Wd, x = (int)idx - ((int)idx / Wd) * Wd;
            const int ylo = max(y - 2, 0), yhi = min(y + 2, Hd - 1);
            const int xlo = max(x - 2, 0), xhi = min(x + 2, Wd - 1);
            float wm = -INFINITY;
            for (int yy = ylo; yy <= yhi; ++yy)
                for (int xx = xlo; xx <= xhi; ++xx)
                    wm = fmaxf(wm, hp[yy * Wd + xx]);
            if (v == wm) {
                const int q = atomicAdd(&s_scnt, 1);
                S[q] = k;   // q < cnt <= SCAP
            }
        }
    }
    __syncthreads();
    const int sc = s_scnt;

    if (!over && sc >= KK) {
        // Prefix-closed survivor set -> in-set rank == global rank. Exact.
        for (int idx = tid; idx < sc; idx += 512) {
            const unsigned long long k = S[idx];
            int r = 0;
            for (int j = 0; j < sc; ++j) r += (S[j] > k) ? 1 : 0;
            if (r < KK) planeKeys[p * KK + r] = k;
        }
        return;
    }

    // Fallback (any-data correct): brute-force full-plane NMS + keyed argmax.
    if (tid == 0) fbCnt[p] = 0;
    for (int j = tid; j < KK; j += 512) planeKeys[p * KK + j] = 0;
    __syncthreads();
    unsigned long long* fb = fbBuf + (size_t)p * FB_CAP;
    for (int px = tid; px < HW; px += 512) {
        const float v = hp[px];
        const int y = px / Wd, x = px - (px / Wd) * Wd;
        const int ylo = max(y - 2, 0), yhi = min(y + 2, Hd - 1);
        const int xlo = max(x - 2, 0), xhi = min(x + 2, Wd - 1);
        float wm = -INFINITY;
        for (int yy = ylo; yy <= yhi; ++yy)
            for (int xx = xlo; xx <= xhi; ++xx)
                wm = fmaxf(wm, hp[yy * Wd + xx]);
        if (v == wm) {
            const int q = atomicAdd(&fbCnt[p], 1);
            if (q < FB_CAP) fb[q] = mkkey(v, (unsigned int)px);
        }
    }
    __syncthreads();
    const int nn = min(fbCnt[p], FB_CAP);
    unsigned long long prevk = ~0ull;
    for (int it = 0; it < KK; ++it) {
        unsigned long long mk = 0;
        for (int j = tid; j < nn; j += 512) {
            unsigned long long k = fb[j];
            if (k == prevk) { fb[j] = 0; k = 0; }
            if (k > mk) mk = k;
        }
        for (int s = 32; s > 0; s >>= 1) {
            const unsigned long long o = __shfl_down(mk, s);
            if (o > mk) mk = o;
        }
        if (lane == 0) wmax[wid] = mk;
        __syncthreads();
        if (tid == 0) {
            unsigned long long m = wmax[0];
            for (int w = 1; w < 8; ++w) if (wmax[w] > m) m = wmax[w];
            planeKeys[p * KK + it] = m;
            sprev = m;
        }
        __syncthreads();
        prevk = sprev;
    }
}

// Kernel 2: one block per detection (800 x 256). Each block redundantly ranks
// all 16 batches' 450 planeKeys into LDS det arrays (order-independent,
// deterministic), then computes the batch-global segment-max valid flag and
// its own detection's math + writes. No cross-block fresh-data reads.
__global__ __launch_bounds__(256) void finalize_all(const unsigned long long* __restrict__ planeKeys,
                                                    const float* __restrict__ regs,
                                                    const float* __restrict__ calib,
                                                    float* __restrict__ out) {
    __shared__ unsigned long long bk[NK];     // 3.6 KB
    __shared__ unsigned int bsidx[NK];        // 1.8 KB
    __shared__ float detSc[NDET];             // 3.2 KB
    __shared__ int detInd[NDET];              // 3.2 KB
    __shared__ int detCl[NDET];               // 3.2 KB
    __shared__ float s26[26];
    __shared__ float wred[4];

    const int i = blockIdx.x;
    const int tid = threadIdx.x;
    const int lane = tid & 63, wid = tid >> 6;
    const int b = i / KK;

    // Rank each batch's 450 keys -> det arrays (16 x ~790 cmp/thread).
    for (int bb = 0; bb < NB; ++bb) {
        __syncthreads();  // protect bk reuse
        for (int j = tid; j < NK; j += 256) {
            const unsigned long long pk = planeKeys[bb * NK + j];
            bsidx[j] = 0xFFFFFFFFu - (unsigned int)(pk & 0xFFFFFFFFull);
            bk[j] = (pk & 0xFFFFFFFF00000000ull) | (unsigned long long)(0xFFFFFFFFu - (unsigned int)j);
        }
        __syncthreads();
        for (int idx = tid; idx < NK; idx += 256) {
            const unsigned long long k = bk[idx];
            int r = 0;
            for (int j = 0; j < NK; ++j) r += (bk[j] > k) ? 1 : 0;
            if (r < KK) {
                detSc[bb * KK + r] = __uint_as_float((unsigned int)(k >> 32));
                detInd[bb * KK + r] = (int)bsidx[idx];
                detCl[bb * KK + r] = idx / KK;
            }
        }
    }
    __syncthreads();

    // Own detection.
    const int ind0 = detInd[i];
    const int ind = (ind0 >= 0 && ind0 < HW) ? ind0 : 0;
    if (tid < 26) {
        const int ch = (tid < 6) ? tid : tid + 16;  // 0-5, 22-24, 25-40, 41
        s26[tid] = regs[(size_t)b * 46 * HW + (size_t)ch * HW + (size_t)ind];
    }

    // Batch-global segment-max over spatial index (reference segment_max).
    float m = -INFINITY;
    for (int j = tid; j < NDET; j += 256) {
        if (detInd[j] == ind0 && detSc[j] >= 0.29f) {
            m = fmaxf(m, (float)detCl[j] * 10000.0f - (float)j);
        }
    }
#pragma unroll
    for (int s = 32; s > 0; s >>= 1) m = fmaxf(m, __shfl_down(m, s));
    if (lane == 0) wred[wid] = m;
    __syncthreads();
    if (tid != 0) return;

    m = fmaxf(fmaxf(wred[0], wred[1]), fmaxf(wred[2], wred[3]));
    const float* s = s26;
    const int cls = detCl[i];
    const float score = detSc[i];
    const bool th = score >= 0.29f;
    const float key_i = th ? (float)cls * 10000.0f - (float)i : -INFINITY;
    const bool valid = th && (key_i == m);

    const float x = (float)(ind % Wd);
    const float y = (float)(ind / Wd);
    const float r0 = fmaxf(s[0], 0.0f), r1 = fmaxf(s[1], 0.0f);
    const float r2 = fmaxf(s[2], 0.0f), r3 = fmaxf(s[3], 0.0f);
    const float cx = x + s[4];
    const float cy = y + s[5];

    const float bx1 = fminf(fmaxf((cx - r0) * 4.0f, 0.0f), 1920.0f);
    const float by1 = fminf(fmaxf((cy - r1) * 4.0f, 0.0f), 1056.0f);
    const float bx2 = fminf(fmaxf((cx + r2) * 4.0f, 0.0f), 1920.0f);
    const float by2 = fminf(fmaxf((cy + r3) * 4.0f, 0.0f), 1056.0f);

    const float dim0 = expf(s[6]) * DIMM[cls][0];
    const float dim1 = expf(s[7]) * DIMM[cls][1];
    const float dim2 = expf(s[8]) * DIMM[cls][2];

    const float sig = 1.0f / (1.0f + expf(-s[25]));
    const float depth = fminf(fmaxf(1.0f / sig - 1.0f, 0.1f), 200.0f);

    const float fu = calib[0], cu = calib[2], fv = calib[5], cv = calib[6];
    const float bxo = calib[3] / -fu;
    const float byo = calib[7] / -fv;
    const float locx = (cx * 4.0f - cu) * depth / fu + bxo;
    const float locy = (cy * 4.0f - cv) * depth / fv + byo;

    float best = -INFINITY;
    int bidx = 0;
#pragma unroll
    for (int t = 0; t < 4; ++t) {
        const float l0 = s[9 + 2 * t], l1 = s[9 + 2 * t + 1];
        const float mm = fmaxf(l0, l1);
        const float p1 = expf(l1 - mm) / (expf(l0 - mm) + expf(l1 - mm));
        if (p1 > best) { best = p1; bidx = t; }
    }
    const float sel0 = s[17 + 2 * bidx], sel1 = s[17 + 2 * bidx + 1];
    float alpha = atanf(sel0 / sel1) + ACENT[bidx];
    const float ray = atanf(locx / depth);
    float roty = alpha + ray;
    if (roty > PI_F) roty -= TWO_PI_F;
    if (roty < -PI_F) roty += TWO_PI_F;
    if (alpha > PI_F) alpha -= TWO_PI_F;
    if (alpha < -PI_F) alpha += TWO_PI_F;

    float* o = out + (size_t)i * 14;
    o[0] = bx1; o[1] = by1; o[2] = bx2; o[3] = by2;
    o[4] = dim0; o[5] = dim1; o[6] = dim2;
    o[7] = depth;
    o[8] = locx; o[9] = locy; o[10] = depth;
    o[11] = roty; o[12] = alpha;
    o[13] = score;
    out[NDET * 14 + i] = valid ? 1.0f : 0.0f;
    out[NDET * 15 + i] = (float)cls;
}

extern "C" void kernel_launch(void* const* d_in, const int* in_sizes, int n_in,
                              void* d_out, int out_size, void* d_ws, size_t ws_size,
                              hipStream_t stream) {
    const float* cls = (const float*)d_in[0];
    const float* regs = (const float*)d_in[1];
    const float* calib = (const float*)d_in[2];
    float* out = (float*)d_out;
    char* ws = (char*)d_ws;

    // ws layout (all regions rewritten each launch before being read)
    unsigned long long* planeKeys = (unsigned long long*)ws;           // 144*50*8 = 57,600 B
    int* fbCnt = (int*)(ws + 65536);                                   // 144*4
    unsigned long long* fbBuf = (unsigned long long*)(ws + 98304);     // 144*16384*8 = 18,874,368 B

    hipLaunchKernelGGL(plane_select, dim3(NPLANE), dim3(512), 0, stream, cls, planeKeys, fbBuf, fbCnt);
    hipLaunchKernelGGL(finalize_all, dim3(NDET), dim3(256), 0, stream, planeKeys, regs, calib, out);
}

// Round 18
// 62.609 us; speedup vs baseline: 5.1104x; 5.1104x over previous
//
#include <hip/hip_runtime.h>
#include <math.h>

#define Hd 264
#define Wd 480
#define HW (Hd * Wd)
#define NB 16
#define NC 9
#define KK 50
#define NPLANE 144
#define NDET 800
#define NK 450
#define SCAP 1024
#define FB_CAP 16384
#define TB_F 0.998f
#define PI_F 3.14159274101257324f
#define TWO_PI_F 6.28318548202514648f

__device__ const float DIMM[9][3] = {
    {3.99331126f, 1.54370861f, 1.64175497f},
    {0.295f, 1.6f, 0.3175f},
    {1.34645161f, 1.55322581f, 0.3883871f},
    {2.503f, 1.72f, 1.077f},
    {9.1775f, 2.95f, 2.3425f},
    {10.3655102f, 3.31632653f, 2.45469388f},
    {6.016911083f, 3.412001685f, 2.2783185f},
    {4.824963f, 2.046904f, 1.78939f},
    {8.8040879f, 2.916193f, 2.07649252f}};

__device__ const float ACENT[4] = {0.0f, 1.57079637050628662f, 3.14159274101257324f, -1.57079637050628662f};

__device__ __forceinline__ unsigned long long mkkey(float v, unsigned int idx) {
    return ((unsigned long long)__float_as_uint(v) << 32) | (unsigned long long)(0xFFFFFFFFu - idx);
}

// Kernel 1 (R17 K1 verbatim, proven): one block per plane (144 x 512).
// Stream plane -> threshold >= TB into LDS -> NMS-verify via direct 25-point
// window reads -> exact rank -> planeKeys. Block-local; replay-safe
// (rank-addressed output is order-independent). Keys = (value<<32)|~idx.
__global__ __launch_bounds__(512) void plane_select(const float* __restrict__ cls,
                                                    unsigned long long* __restrict__ planeKeys,
                                                    unsigned long long* __restrict__ fbBuf,
                                                    int* __restrict__ fbCnt) {
    __shared__ unsigned long long cand[SCAP];
    __shared__ unsigned long long S[SCAP];
    __shared__ int s_cnt, s_scnt;
    __shared__ unsigned long long wmax[8];
    __shared__ unsigned long long sprev;

    const int p = blockIdx.x;
    const int tid = threadIdx.x;
    const int lane = tid & 63, wid = tid >> 6;
    const float* hp = cls + (size_t)p * HW;
    const float4* hp4 = (const float4*)hp;

    if (tid == 0) { s_cnt = 0; s_scnt = 0; }
    __syncthreads();

    for (int q = tid; q < HW / 4; q += 512) {
        const float4 v = hp4[q];
        const unsigned int i0 = 4u * (unsigned int)q;
        if (v.x >= TB_F) { const int c = atomicAdd(&s_cnt, 1); if (c < SCAP) cand[c] = mkkey(v.x, i0); }
        if (v.y >= TB_F) { const int c = atomicAdd(&s_cnt, 1); if (c < SCAP) cand[c] = mkkey(v.y, i0 + 1); }
        if (v.z >= TB_F) { const int c = atomicAdd(&s_cnt, 1); if (c < SCAP) cand[c] = mkkey(v.z, i0 + 2); }
        if (v.w >= TB_F) { const int c = atomicAdd(&s_cnt, 1); if (c < SCAP) cand[c] = mkkey(v.w, i0 + 3); }
    }
    __syncthreads();
    const int cnt = s_cnt;
    const bool over = cnt > SCAP;

    if (!over) {
        for (int j = tid; j < cnt; j += 512) {
            const unsigned long long k = cand[j];
            const unsigned int idx = 0xFFFFFFFFu - (unsigned int)(k & 0xFFFFFFFFull);
            const float v = __uint_as_float((unsigned int)(k >> 32));
            const int y = (int)idx / Wd, x = (int)idx - ((int)idx / Wd) * Wd;
            const int ylo = max(y - 2, 0), yhi = min(y + 2, Hd - 1);
            const int xlo = max(x - 2, 0), xhi = min(x + 2, Wd - 1);
            float wm = -INFINITY;
            for (int yy = ylo; yy <= yhi; ++yy)
                for (int xx = xlo; xx <= xhi; ++xx)
                    wm = fmaxf(wm, hp[yy * Wd + xx]);
            if (v == wm) {
                const int q = atomicAdd(&s_scnt, 1);
                S[q] = k;
            }
        }
    }
    __syncthreads();
    const int sc = s_scnt;

    if (!over && sc >= KK) {
        for (int idx = tid; idx < sc; idx += 512) {
            const unsigned long long k = S[idx];
            int r = 0;
            for (int j = 0; j < sc; ++j) r += (S[j] > k) ? 1 : 0;
            if (r < KK) planeKeys[p * KK + r] = k;
        }
        return;
    }

    // Fallback (any-data correct): brute-force full-plane NMS + keyed argmax.
    if (tid == 0) fbCnt[p] = 0;
    for (int j = tid; j < KK; j += 512) planeKeys[p * KK + j] = 0;
    __syncthreads();
    unsigned long long* fb = fbBuf + (size_t)p * FB_CAP;
    for (int px = tid; px < HW; px += 512) {
        const float v = hp[px];
        const int y = px / Wd, x = px - (px / Wd) * Wd;
        const int ylo = max(y - 2, 0), yhi = min(y + 2, Hd - 1);
        const int xlo = max(x - 2, 0), xhi = min(x + 2, Wd - 1);
        float wm = -INFINITY;
        for (int yy = ylo; yy <= yhi; ++yy)
            for (int xx = xlo; xx <= xhi; ++xx)
                wm = fmaxf(wm, hp[yy * Wd + xx]);
        if (v == wm) {
            const int q = atomicAdd(&fbCnt[p], 1);
            if (q < FB_CAP) fb[q] = mkkey(v, (unsigned int)px);
        }
    }
    __syncthreads();
    const int nn = min(fbCnt[p], FB_CAP);
    unsigned long long prevk = ~0ull;
    for (int it = 0; it < KK; ++it) {
        unsigned long long mk = 0;
        for (int j = tid; j < nn; j += 512) {
            unsigned long long k = fb[j];
            if (k == prevk) { fb[j] = 0; k = 0; }
            if (k > mk) mk = k;
        }
        for (int s = 32; s > 0; s >>= 1) {
            const unsigned long long o = __shfl_down(mk, s);
            if (o > mk) mk = o;
        }
        if (lane == 0) wmax[wid] = mk;
        __syncthreads();
        if (tid == 0) {
            unsigned long long m = wmax[0];
            for (int w = 1; w < 8; ++w) if (wmax[w] > m) m = wmax[w];
            planeKeys[p * KK + it] = m;
            sprev = m;
        }
        __syncthreads();
        prevk = sprev;
    }
}

// Kernel 2 (R15 verbatim): per batch — exact top-50 of 450 unique keys.
__global__ __launch_bounds__(256) void batch_topk(const unsigned long long* __restrict__ planeKeys,
                                                  float* __restrict__ dScore, int* __restrict__ dInd,
                                                  int* __restrict__ dCls) {
    __shared__ unsigned long long k2[NK];
    __shared__ unsigned int sidx[NK];

    const int b = blockIdx.x;
    const int tid = threadIdx.x;
    for (int j = tid; j < NK; j += 256) {
        const unsigned long long pk = planeKeys[b * NK + j];
        sidx[j] = 0xFFFFFFFFu - (unsigned int)(pk & 0xFFFFFFFFull);
        k2[j] = (pk & 0xFFFFFFFF00000000ull) | (unsigned long long)(0xFFFFFFFFu - (unsigned int)j);
    }
    __syncthreads();

    for (int idx = tid; idx < NK; idx += 256) {
        const unsigned long long k = k2[idx];
        int r = 0;
        for (int j = 0; j < NK; ++j) r += (k2[j] > k) ? 1 : 0;
        if (r < KK) {
            dScore[b * KK + r] = __uint_as_float((unsigned int)(k >> 32));
            dInd[b * KK + r] = (int)sidx[idx];
            dCls[b * KK + r] = idx / KK;
        }
    }
}

// Kernel 3 (R15 verbatim): fused per-detection finalize, 800 blocks x 64.
__global__ __launch_bounds__(64) void finalize(const float* __restrict__ regs,
                                               const float* __restrict__ calib,
                                               const float* __restrict__ dScore,
                                               const int* __restrict__ dInd,
                                               const int* __restrict__ dCls,
                                               float* __restrict__ out) {
    __shared__ float s[26];
    const int i = blockIdx.x;
    const int lane = threadIdx.x;
    const int ind0 = dInd[i];
    const int ind = (ind0 >= 0 && ind0 < HW) ? ind0 : 0;
    const int b = i / KK;

    if (lane < 26) {
        const int ch = (lane < 6) ? lane : lane + 16;  // 0-5, 22-24, 25-40, 41
        s[lane] = regs[(size_t)b * 46 * HW + (size_t)ch * HW + (size_t)ind];
    }

    float m = -INFINITY;
    for (int j = lane; j < NDET; j += 64) {
        if (dInd[j] == ind0 && dScore[j] >= 0.29f) {
            m = fmaxf(m, (float)dCls[j] * 10000.0f - (float)j);
        }
    }
#pragma unroll
    for (int sft = 32; sft > 0; sft >>= 1) m = fmaxf(m, __shfl_down(m, sft));
    __syncthreads();
    if (lane != 0) return;

    const int cls = dCls[i];
    const float score = dScore[i];
    const bool th = score >= 0.29f;
    const float key_i = th ? (float)cls * 10000.0f - (float)i : -INFINITY;
    const bool valid = th && (key_i == m);

    const float x = (float)(ind % Wd);
    const float y = (float)(ind / Wd);

    const float r0 = fmaxf(s[0], 0.0f), r1 = fmaxf(s[1], 0.0f);
    const float r2 = fmaxf(s[2], 0.0f), r3 = fmaxf(s[3], 0.0f);
    const float cx = x + s[4];
    const float cy = y + s[5];

    const float bx1 = fminf(fmaxf((cx - r0) * 4.0f, 0.0f), 1920.0f);
    const float by1 = fminf(fmaxf((cy - r1) * 4.0f, 0.0f), 1056.0f);
    const float bx2 = fminf(fmaxf((cx + r2) * 4.0f, 0.0f), 1920.0f);
    const float by2 = fminf(fmaxf((cy + r3) * 4.0f, 0.0f), 1056.0f);

    const float dim0 = expf(s[6]) * DIMM[cls][0];
    const float dim1 = expf(s[7]) * DIMM[cls][1];
    const float dim2 = expf(s[8]) * DIMM[cls][2];

    const float sig = 1.0f / (1.0f + expf(-s[25]));
    const float depth = fminf(fmaxf(1.0f / sig - 1.0f, 0.1f), 200.0f);

    const float fu = calib[0], cu = calib[2], fv = calib[5], cv = calib[6];
    const float bxo = calib[3] / -fu;
    const float byo = calib[7] / -fv;
    const float locx = (cx * 4.0f - cu) * depth / fu + bxo;
    const float locy = (cy * 4.0f - cv) * depth / fv + byo;

    float best = -INFINITY;
    int bidx = 0;
#pragma unroll
    for (int t = 0; t < 4; ++t) {
        const float l0 = s[9 + 2 * t], l1 = s[9 + 2 * t + 1];
        const float mm = fmaxf(l0, l1);
        const float p1 = expf(l1 - mm) / (expf(l0 - mm) + expf(l1 - mm));
        if (p1 > best) { best = p1; bidx = t; }
    }
    const float sel0 = s[17 + 2 * bidx], sel1 = s[17 + 2 * bidx + 1];
    float alpha = atanf(sel0 / sel1) + ACENT[bidx];
    const float ray = atanf(locx / depth);
    float roty = alpha + ray;
    if (roty > PI_F) roty -= TWO_PI_F;
    if (roty < -PI_F) roty += TWO_PI_F;
    if (alpha > PI_F) alpha -= TWO_PI_F;
    if (alpha < -PI_F) alpha += TWO_PI_F;

    float* o = out + (size_t)i * 14;
    o[0] = bx1; o[1] = by1; o[2] = bx2; o[3] = by2;
    o[4] = dim0; o[5] = dim1; o[6] = dim2;
    o[7] = depth;
    o[8] = locx; o[9] = locy; o[10] = depth;
    o[11] = roty; o[12] = alpha;
    o[13] = score;
    out[NDET * 14 + i] = valid ? 1.0f : 0.0f;
    out[NDET * 15 + i] = (float)cls;
}

extern "C" void kernel_launch(void* const* d_in, const int* in_sizes, int n_in,
                              void* d_out, int out_size, void* d_ws, size_t ws_size,
                              hipStream_t stream) {
    const float* cls = (const float*)d_in[0];
    const float* regs = (const float*)d_in[1];
    const float* calib = (const float*)d_in[2];
    float* out = (float*)d_out;
    char* ws = (char*)d_ws;

    // ws layout (all regions rewritten each launch before being read)
    unsigned long long* planeKeys = (unsigned long long*)ws;           // 144*50*8 = 57,600 B
    float* dScore = (float*)(ws + 57600);                              // 3200
    int* dInd = (int*)(ws + 60800);                                    // 3200
    int* dCls = (int*)(ws + 64000);                                    // 3200
    int* fbCnt = (int*)(ws + 67200);                                   // 576
    unsigned long long* fbBuf = (unsigned long long*)(ws + 98304);     // 144*16384*8 = 18,874,368 B

    hipLaunchKernelGGL(plane_select, dim3(NPLANE), dim3(512), 0, stream, cls, planeKeys, fbBuf, fbCnt);
    hipLaunchKernelGGL(batch_topk, dim3(NB), dim3(256), 0, stream, planeKeys, dScore, dInd, dCls);
    hipLaunchKernelGGL(finalize, dim3(NDET), dim3(64), 0, stream, regs, calib, dScore, dInd, dCls, out);
}

// Round 19
// 59.493 us; speedup vs baseline: 5.3780x; 1.0524x over previous
//
#include <hip/hip_runtime.h>
#include <math.h>

#define Hd 264
#define Wd 480
#define HW (Hd * Wd)
#define NB 16
#define NC 9
#define KK 50
#define NPLANE 144
#define NDET 800
#define NK 450
#define K1CH 8
#define F4PC (HW / 4 / K1CH)       // 3960
#define SLAB_CAP 512
#define SCAP 1024
#define FB_CAP 16384
#define TB_F 0.998f
#define PI_F 3.14159274101257324f
#define TWO_PI_F 6.28318548202514648f

__device__ const float DIMM[9][3] = {
    {3.99331126f, 1.54370861f, 1.64175497f},
    {0.295f, 1.6f, 0.3175f},
    {1.34645161f, 1.55322581f, 0.3883871f},
    {2.503f, 1.72f, 1.077f},
    {9.1775f, 2.95f, 2.3425f},
    {10.3655102f, 3.31632653f, 2.45469388f},
    {6.016911083f, 3.412001685f, 2.2783185f},
    {4.824963f, 2.046904f, 1.78939f},
    {8.8040879f, 2.916193f, 2.07649252f}};

__device__ const float ACENT[4] = {0.0f, 1.57079637050628662f, 3.14159274101257324f, -1.57079637050628662f};

__device__ __forceinline__ unsigned long long mkkey(float v, unsigned int idx) {
    return ((unsigned long long)__float_as_uint(v) << 32) | (unsigned long long)(0xFFFFFFFFu - idx);
}

// Kernel 1: streaming threshold filter (1152 blocks = full-chip HBM bandwidth).
// Pixels >= TB_F appended to per-(plane,chunk) slab + raw count. Replay-safe:
// everything rewritten each launch; no cross-block protocols anywhere.
__global__ __launch_bounds__(256) void thresh_scan(const float* __restrict__ cls,
                                                   unsigned long long* __restrict__ slabs,
                                                   int* __restrict__ slabCnt) {
    __shared__ unsigned long long sbuf[SLAB_CAP];
    __shared__ int scnt;

    const int plane = blockIdx.y;
    const int chunk = blockIdx.x;
    const int tid = threadIdx.x;
    if (tid == 0) scnt = 0;
    __syncthreads();

    const float4* hp4 = (const float4*)(cls + (size_t)plane * HW) + (size_t)chunk * F4PC;
    const unsigned int base = (unsigned int)(chunk * F4PC * 4);

    for (int q = tid; q < F4PC; q += 256) {
        const float4 v = hp4[q];
        const unsigned int i0 = base + 4u * (unsigned int)q;
        if (v.x >= TB_F) { const int p = atomicAdd(&scnt, 1); if (p < SLAB_CAP) sbuf[p] = mkkey(v.x, i0); }
        if (v.y >= TB_F) { const int p = atomicAdd(&scnt, 1); if (p < SLAB_CAP) sbuf[p] = mkkey(v.y, i0 + 1); }
        if (v.z >= TB_F) { const int p = atomicAdd(&scnt, 1); if (p < SLAB_CAP) sbuf[p] = mkkey(v.z, i0 + 2); }
        if (v.w >= TB_F) { const int p = atomicAdd(&scnt, 1); if (p < SLAB_CAP) sbuf[p] = mkkey(v.w, i0 + 3); }
    }
    __syncthreads();
    const int n = min(scnt, SLAB_CAP);
    unsigned long long* dst = slabs + (size_t)(plane * K1CH + chunk) * SLAB_CAP;
    for (int j = tid; j < n; j += 256) dst[j] = sbuf[j];
    if (tid == 0) slabCnt[plane * K1CH + chunk] = scnt;  // raw (overflow-detectable)
}

// Kernel 2: one block per plane — NMS-verify candidates (direct 25-point window
// reads) + exact rank into planeKeys. Block-local; no cross-block reads of
// freshly-written data beyond the kernel boundary (clean-boundary rule).
// Fallback (overflow / <50 survivors): brute-force full-plane NMS + keyed
// argmax via global scratch. Bit-exact keys; prefix-closed -> exact ranks.
__global__ __launch_bounds__(256) void select_topk(const float* __restrict__ cls,
                                                   const unsigned long long* __restrict__ slabs,
                                                   const int* __restrict__ slabCnt,
                                                   unsigned long long* __restrict__ planeKeys,
                                                   unsigned long long* __restrict__ fbBuf,
                                                   int* __restrict__ fbCnt) {
    __shared__ unsigned long long S[SCAP];
    __shared__ int soff[K1CH + 1];
    __shared__ int s_scnt, s_over;
    __shared__ unsigned long long wmax[4];
    __shared__ unsigned long long sprev;

    const int p = blockIdx.x;
    const int tid = threadIdx.x;
    const int lane = tid & 63, wid = tid >> 6;
    const float* hp = cls + (size_t)p * HW;

    if (tid == 0) { s_scnt = 0; s_over = 0; }
    __syncthreads();
    if (tid < K1CH) {
        const int c = slabCnt[p * K1CH + tid];
        soff[tid + 1] = min(c, SLAB_CAP);
        if (c > SLAB_CAP) atomicAdd(&s_over, 1);
    }
    __syncthreads();
    if (tid == 0) {
        soff[0] = 0;
        for (int c = 1; c <= K1CH; ++c) soff[c] += soff[c - 1];
    }
    __syncthreads();
    const int n = soff[K1CH];

    if (!s_over) {
        for (int j = tid; j < n; j += 256) {
            int lo = 0, hi = K1CH;
            while (hi - lo > 1) { const int mid = (lo + hi) >> 1; if (soff[mid] <= j) lo = mid; else hi = mid; }
            const unsigned long long k = slabs[(size_t)(p * K1CH + lo) * SLAB_CAP + (j - soff[lo])];
            const unsigned int idx = 0xFFFFFFFFu - (unsigned int)(k & 0xFFFFFFFFull);
            const float v = __uint_as_float((unsigned int)(k >> 32));
            const int y = (int)idx / Wd, x = (int)idx - ((int)idx / Wd) * Wd;
            const int ylo = max(y - 2, 0), yhi = min(y + 2, Hd - 1);
            const int xlo = max(x - 2, 0), xhi = min(x + 2, Wd - 1);
            float wm = -INFINITY;
            for (int yy = ylo; yy <= yhi; ++yy)
                for (int xx = xlo; xx <= xhi; ++xx)
                    wm = fmaxf(wm, hp[yy * Wd + xx]);
            if (v == wm) {
                const int q = atomicAdd(&s_scnt, 1);
                if (q < SCAP) S[q] = k;
            }
        }
    }
    __syncthreads();
    const int sc = s_scnt;

    if (!s_over && sc >= KK && sc <= SCAP) {
        // Prefix-closed survivor set -> in-set rank == global rank. Exact.
        for (int idx = tid; idx < sc; idx += 256) {
            const unsigned long long k = S[idx];
            int r = 0;
            for (int j = 0; j < sc; ++j) r += (S[j] > k) ? 1 : 0;
            if (r < KK) planeKeys[p * KK + r] = k;
        }
        return;
    }

    // Fallback (any-data correct): brute-force full-plane NMS + keyed argmax.
    if (tid == 0) fbCnt[p] = 0;
    for (int j = tid; j < KK; j += 256) planeKeys[p * KK + j] = 0;
    __syncthreads();
    unsigned long long* fb = fbBuf + (size_t)p * FB_CAP;
    for (int px = tid; px < HW; px += 256) {
        const float v = hp[px];
        const int y = px / Wd, x = px - (px / Wd) * Wd;
        const int ylo = max(y - 2, 0), yhi = min(y + 2, Hd - 1);
        const int xlo = max(x - 2, 0), xhi = min(x + 2, Wd - 1);
        float wm = -INFINITY;
        for (int yy = ylo; yy <= yhi; ++yy)
            for (int xx = xlo; xx <= xhi; ++xx)
                wm = fmaxf(wm, hp[yy * Wd + xx]);
        if (v == wm) {
            const int q = atomicAdd(&fbCnt[p], 1);
            if (q < FB_CAP) fb[q] = mkkey(v, (unsigned int)px);
        }
    }
    __syncthreads();
    const int nn = min(fbCnt[p], FB_CAP);
    unsigned long long prevk = ~0ull;
    for (int it = 0; it < KK; ++it) {
        unsigned long long mk = 0;
        for (int j = tid; j < nn; j += 256) {
            unsigned long long k = fb[j];
            if (k == prevk) { fb[j] = 0; k = 0; }
            if (k > mk) mk = k;
        }
        for (int s = 32; s > 0; s >>= 1) {
            const unsigned long long o = __shfl_down(mk, s);
            if (o > mk) mk = o;
        }
        if (lane == 0) wmax[wid] = mk;
        __syncthreads();
        if (tid == 0) {
            unsigned long long m = wmax[0];
            if (wmax[1] > m) m = wmax[1];
            if (wmax[2] > m) m = wmax[2];
            if (wmax[3] > m) m = wmax[3];
            planeKeys[p * KK + it] = m;
            sprev = m;
        }
        __syncthreads();
        prevk = sprev;
    }
}

// Kernel 3: per batch — exact top-50 of 450 unique keys by direct ranking.
__global__ __launch_bounds__(256) void batch_topk(const unsigned long long* __restrict__ planeKeys,
                                                  float* __restrict__ dScore, int* __restrict__ dInd,
                                                  int* __restrict__ dCls) {
    __shared__ unsigned long long k2[NK];
    __shared__ unsigned int sidx[NK];

    const int b = blockIdx.x;
    const int tid = threadIdx.x;
    for (int j = tid; j < NK; j += 256) {
        const unsigned long long pk = planeKeys[b * NK + j];
        sidx[j] = 0xFFFFFFFFu - (unsigned int)(pk & 0xFFFFFFFFull);
        k2[j] = (pk & 0xFFFFFFFF00000000ull) | (unsigned long long)(0xFFFFFFFFu - (unsigned int)j);
    }
    __syncthreads();

    for (int idx = tid; idx < NK; idx += 256) {
        const unsigned long long k = k2[idx];
        int r = 0;
        for (int j = 0; j < NK; ++j) r += (k2[j] > k) ? 1 : 0;
        if (r < KK) {
            dScore[b * KK + r] = __uint_as_float((unsigned int)(k >> 32));
            dInd[b * KK + r] = (int)sidx[idx];
            dCls[b * KK + r] = idx / KK;
        }
    }
}

// Kernel 4: fused per-detection finalize, 800 blocks x 64. Lanes <26 issue the
// scattered reg loads; all 64 lanes run the batch-global segment-max; lane 0
// does the math + all writes (incl. valid flag).
__global__ __launch_bounds__(64) void finalize(const float* __restrict__ regs,
                                               const float* __restrict__ calib,
                                               const float* __restrict__ dScore,
                                               const int* __restrict__ dInd,
                                               const int* __restrict__ dCls,
                                               float* __restrict__ out) {
    __shared__ float s[26];
    const int i = blockIdx.x;
    const int lane = threadIdx.x;
    const int ind0 = dInd[i];
    const int ind = (ind0 >= 0 && ind0 < HW) ? ind0 : 0;
    const int b = i / KK;

    if (lane < 26) {
        const int ch = (lane < 6) ? lane : lane + 16;  // 0-5, 22-24, 25-40, 41
        s[lane] = regs[(size_t)b * 46 * HW + (size_t)ch * HW + (size_t)ind];
    }

    float m = -INFINITY;
    for (int j = lane; j < NDET; j += 64) {
        if (dInd[j] == ind0 && dScore[j] >= 0.29f) {
            m = fmaxf(m, (float)dCls[j] * 10000.0f - (float)j);
        }
    }
#pragma unroll
    for (int sft = 32; sft > 0; sft >>= 1) m = fmaxf(m, __shfl_down(m, sft));
    __syncthreads();
    if (lane != 0) return;

    const int cls = dCls[i];
    const float score = dScore[i];
    const bool th = score >= 0.29f;
    const float key_i = th ? (float)cls * 10000.0f - (float)i : -INFINITY;
    const bool valid = th && (key_i == m);

    const float x = (float)(ind % Wd);
    const float y = (float)(ind / Wd);

    const float r0 = fmaxf(s[0], 0.0f), r1 = fmaxf(s[1], 0.0f);
    const float r2 = fmaxf(s[2], 0.0f), r3 = fmaxf(s[3], 0.0f);
    const float cx = x + s[4];
    const float cy = y + s[5];

    const float bx1 = fminf(fmaxf((cx - r0) * 4.0f, 0.0f), 1920.0f);
    const float by1 = fminf(fmaxf((cy - r1) * 4.0f, 0.0f), 1056.0f);
    const float bx2 = fminf(fmaxf((cx + r2) * 4.0f, 0.0f), 1920.0f);
    const float by2 = fminf(fmaxf((cy + r3) * 4.0f, 0.0f), 1056.0f);

    const float dim0 = expf(s[6]) * DIMM[cls][0];
    const float dim1 = expf(s[7]) * DIMM[cls][1];
    const float dim2 = expf(s[8]) * DIMM[cls][2];

    const float sig = 1.0f / (1.0f + expf(-s[25]));
    const float depth = fminf(fmaxf(1.0f / sig - 1.0f, 0.1f), 200.0f);

    const float fu = calib[0], cu = calib[2], fv = calib[5], cv = calib[6];
    const float bxo = calib[3] / -fu;
    const float byo = calib[7] / -fv;
    const float locx = (cx * 4.0f - cu) * depth / fu + bxo;
    const float locy = (cy * 4.0f - cv) * depth / fv + byo;

    float best = -INFINITY;
    int bidx = 0;
#pragma unroll
    for (int t = 0; t < 4; ++t) {
        const float l0 = s[9 + 2 * t], l1 = s[9 + 2 * t + 1];
        const float mm = fmaxf(l0, l1);
        const float p1 = expf(l1 - mm) / (expf(l0 - mm) + expf(l1 - mm));
        if (p1 > best) { best = p1; bidx = t; }
    }
    const float sel0 = s[17 + 2 * bidx], sel1 = s[17 + 2 * bidx + 1];
    float alpha = atanf(sel0 / sel1) + ACENT[bidx];
    const float ray = atanf(locx / depth);
    float roty = alpha + ray;
    if (roty > PI_F) roty -= TWO_PI_F;
    if (roty < -PI_F) roty += TWO_PI_F;
    if (alpha > PI_F) alpha -= TWO_PI_F;
    if (alpha < -PI_F) alpha += TWO_PI_F;

    float* o = out + (size_t)i * 14;
    o[0] = bx1; o[1] = by1; o[2] = bx2; o[3] = by2;
    o[4] = dim0; o[5] = dim1; o[6] = dim2;
    o[7] = depth;
    o[8] = locx; o[9] = locy; o[10] = depth;
    o[11] = roty; o[12] = alpha;
    o[13] = score;
    out[NDET * 14 + i] = valid ? 1.0f : 0.0f;
    out[NDET * 15 + i] = (float)cls;
}

extern "C" void kernel_launch(void* const* d_in, const int* in_sizes, int n_in,
                              void* d_out, int out_size, void* d_ws, size_t ws_size,
                              hipStream_t stream) {
    const float* cls = (const float*)d_in[0];
    const float* regs = (const float*)d_in[1];
    const float* calib = (const float*)d_in[2];
    float* out = (float*)d_out;
    char* ws = (char*)d_ws;

    // ws layout (all regions rewritten each launch before being read)
    int* slabCnt = (int*)ws;                                           // 1152*4 B
    int* fbCnt = (int*)(ws + 8192);                                    // 144*4
    unsigned long long* planeKeys = (unsigned long long*)(ws + 16384); // 57,600 B
    float* dScore = (float*)(ws + 73984);                              // 3200
    int* dInd = (int*)(ws + 77184);                                    // 3200
    int* dCls = (int*)(ws + 80384);                                    // 3200
    unsigned long long* slabs = (unsigned long long*)(ws + 98304);     // 1152*512*8 = 4,718,592
    unsigned long long* fbBuf = (unsigned long long*)(ws + 98304 + 4718592);  // 144*16384*8

    hipLaunchKernelGGL(thresh_scan, dim3(K1CH, NPLANE), dim3(256), 0, stream, cls, slabs, slabCnt);
    hipLaunchKernelGGL(select_topk, dim3(NPLANE), dim3(256), 0, stream, cls, slabs, slabCnt,
                       planeKeys, fbBuf, fbCnt);
    hipLaunchKernelGGL(batch_topk, dim3(NB), dim3(256), 0, stream, planeKeys, dScore, dInd, dCls);
    hipLaunchKernelGGL(finalize, dim3(NDET), dim3(64), 0, stream, regs, calib, dScore, dInd, dCls, out);
}